// Round 1
// baseline (1176.139 us; speedup 1.0000x reference)
//
#include <hip/hip_runtime.h>

// Problem dims
#define DM 32000   // vocab
#define DN 2048    // hidden
#define DD 1024    // embed dim
#define DB 2048    // batch
#define DKG 3072   // N + DIM

typedef __attribute__((ext_vector_type(4))) float floatx4;
typedef __attribute__((ext_vector_type(8))) short shortx8;
typedef __attribute__((ext_vector_type(4))) short shortx4;

__device__ inline unsigned int f2bf(float f) {
    unsigned int u = __builtin_bit_cast(unsigned int, f);
    u += 0x7fffu + ((u >> 16) & 1u);   // round-to-nearest-even
    return u >> 16;
}

__device__ inline float fast_sigmoid(float x) { return 1.0f / (1.0f + __expf(-x)); }
__device__ inline float fast_tanh(float x) { return 1.0f - 2.0f / (__expf(2.0f * x) + 1.0f); }

// ---------------------------------------------------------------------------
// h_prev [N, B] f32  ->  z_t[b][k] bf16 for k in [0, 2048)   (64x64 LDS transpose)
// ---------------------------------------------------------------------------
__global__ __launch_bounds__(256) void transpose_h_kernel(
    const float* __restrict__ h_prev, unsigned short* __restrict__ z_t)
{
    __shared__ unsigned short T[64 * 66];   // stride 66: conflict-free both phases
    int t = threadIdx.x;
    int b0 = blockIdx.x * 64, k0 = blockIdx.y * 64;
    int bi = t & 63, wv = t >> 6;
    #pragma unroll
    for (int i = 0; i < 16; i++) {
        int kl = wv + i * 4;
        float v = h_prev[(size_t)(k0 + kl) * DB + b0 + bi];
        T[kl * 66 + bi] = (unsigned short)f2bf(v);
    }
    __syncthreads();
    #pragma unroll
    for (int i = 0; i < 16; i++) {
        int r = wv + i * 4;   // local b index
        z_t[(size_t)(b0 + r) * DKG + k0 + bi] = T[bi * 66 + r];
    }
}

// ---------------------------------------------------------------------------
// z_t[b][2048 + d] = bf16(emb[input_text[b]][d])  — one block per b
// ---------------------------------------------------------------------------
__global__ __launch_bounds__(256) void emb_gather_kernel(
    const int* __restrict__ idx, const float* __restrict__ emb,
    unsigned short* __restrict__ z_t)
{
    int b = blockIdx.x;
    int row = idx[b];
    int t = threadIdx.x;
    const floatx4 v = *(const floatx4*)(&emb[(size_t)row * DD + t * 4]);
    unsigned int p0 = (f2bf(v[1]) << 16) | f2bf(v[0]);
    unsigned int p1 = (f2bf(v[3]) << 16) | f2bf(v[2]);
    *(uint2*)(&z_t[(size_t)b * DKG + DN + t * 4]) = make_uint2(p0, p1);
}

// ---------------------------------------------------------------------------
// C[m][b] = A[m][:] . Bt[b][:] (+bias[m]); A f32 [M,K] row-major (staged->bf16),
// Bt bf16 [B,K] row-major. 128x128x32 tiles, mfma_f32_16x16x32_bf16.
// blockIdx.z selects among 4 (A, Cout) pairs for the fused gate launch.
// ---------------------------------------------------------------------------
#define BM 128
#define BN 128
#define BK 32
#define LS 40   // LDS row stride (bf16): r*80 mod 128 covers all 16B slots 2x -> no conflicts

__global__ __launch_bounds__(256, 3) void gemm_bt_kernel(
    const float* __restrict__ A0, const float* __restrict__ A1,
    const float* __restrict__ A2, const float* __restrict__ A3,
    const unsigned short* __restrict__ Bt,
    float* __restrict__ C0, float* __restrict__ C1,
    float* __restrict__ C2, float* __restrict__ C3,
    const float* __restrict__ bias, int K)
{
    __shared__ unsigned short As[BM * LS];
    __shared__ unsigned short Bs[BN * LS];
    int t = threadIdx.x;
    int lane = t & 63, wave = t >> 6;
    int wm = (wave >> 1) * 64, wn = (wave & 1) * 64;
    int zz = blockIdx.z;
    const float* A   = (zz == 0) ? A0 : (zz == 1) ? A1 : (zz == 2) ? A2 : A3;
    float*       Cout = (zz == 0) ? C0 : (zz == 1) ? C1 : (zz == 2) ? C2 : C3;
    size_t m0 = (size_t)blockIdx.y * BM, n0 = (size_t)blockIdx.x * BN;

    floatx4 acc[4][4] = {};

    int sa_row = t >> 3;          // 0..31
    int sa_col = (t & 7) * 4;     // 0,4,..,28
    int sb_row = t >> 2;          // 0..63
    int sb_col = (t & 3) * 8;     // 0,8,16,24
    int mrow = lane & 15;
    int koff = (lane >> 4) * 8;

    for (int k0 = 0; k0 < K; k0 += BK) {
        // stage A tile (f32 -> bf16), 128x32
        #pragma unroll
        for (int i = 0; i < 4; i++) {
            int row = i * 32 + sa_row;
            const floatx4 v = *(const floatx4*)(&A[(m0 + row) * (size_t)K + k0 + sa_col]);
            unsigned int p0 = (f2bf(v[1]) << 16) | f2bf(v[0]);
            unsigned int p1 = (f2bf(v[3]) << 16) | f2bf(v[2]);
            *(uint2*)(&As[row * LS + sa_col]) = make_uint2(p0, p1);
        }
        // stage B tile (already bf16), 128x32, 16B vector copies
        #pragma unroll
        for (int i = 0; i < 2; i++) {
            int row = i * 64 + sb_row;
            *(uint4*)(&Bs[row * LS + sb_col]) =
                *(const uint4*)(&Bt[(n0 + row) * (size_t)K + k0 + sb_col]);
        }
        __syncthreads();

        shortx8 af[4], bfv[4];
        #pragma unroll
        for (int mi = 0; mi < 4; mi++) {
            int o = (wm + mi * 16 + mrow) * LS + koff;
            shortx4 lo = *(const shortx4*)(&As[o]);
            shortx4 hi = *(const shortx4*)(&As[o + 4]);
            af[mi] = __builtin_shufflevector(lo, hi, 0, 1, 2, 3, 4, 5, 6, 7);
        }
        #pragma unroll
        for (int ni = 0; ni < 4; ni++) {
            int o = (wn + ni * 16 + mrow) * LS + koff;
            shortx4 lo = *(const shortx4*)(&Bs[o]);
            shortx4 hi = *(const shortx4*)(&Bs[o + 4]);
            bfv[ni] = __builtin_shufflevector(lo, hi, 0, 1, 2, 3, 4, 5, 6, 7);
        }
        #pragma unroll
        for (int mi = 0; mi < 4; mi++)
            #pragma unroll
            for (int ni = 0; ni < 4; ni++)
                acc[mi][ni] = __builtin_amdgcn_mfma_f32_16x16x32_bf16(
                    af[mi], bfv[ni], acc[mi][ni], 0, 0, 0);
        __syncthreads();
    }

    // epilogue: C/D layout col=lane&15, row=(lane>>4)*4+reg  [m89-verified]
    int cn = lane & 15;
    int rb = (lane >> 4) * 4;
    #pragma unroll
    for (int mi = 0; mi < 4; mi++) {
        #pragma unroll
        for (int r = 0; r < 4; r++) {
            size_t row = m0 + wm + mi * 16 + rb + r;
            float bv = bias ? bias[row] : 0.0f;
            #pragma unroll
            for (int ni = 0; ni < 4; ni++) {
                Cout[row * DB + n0 + wn + ni * 16 + cn] = acc[mi][ni][r] + bv;
            }
        }
    }
}

// ---------------------------------------------------------------------------
// Gate math: f,i,o = sigmoid(P + b), tc = tanh(Pc + bC), C = f*Cp + i*tc,
// h = o*tanh(C). Writes C,h (f32, d_out) and h^T bf16 (ws) via LDS transpose.
// ---------------------------------------------------------------------------
__global__ __launch_bounds__(256) void pointwise_kernel(
    const float* __restrict__ Pf, const float* __restrict__ Pi,
    const float* __restrict__ Po, const float* __restrict__ Pc,
    const float* __restrict__ C_prev,
    const float* __restrict__ b_f, const float* __restrict__ b_i,
    const float* __restrict__ b_o, const float* __restrict__ b_C,
    float* __restrict__ outH, float* __restrict__ outC,
    unsigned short* __restrict__ h_t)
{
    __shared__ unsigned short T[64 * 66];
    int t = threadIdx.x;
    int b0 = blockIdx.x * 64, n0 = blockIdx.y * 64;
    int bi = t & 63, wv = t >> 6;
    #pragma unroll
    for (int i = 0; i < 16; i++) {
        int nl = wv + i * 4;
        size_t idx = (size_t)(n0 + nl) * DB + b0 + bi;
        float f  = fast_sigmoid(Pf[idx] + b_f[n0 + nl]);
        float ii = fast_sigmoid(Pi[idx] + b_i[n0 + nl]);
        float o  = fast_sigmoid(Po[idx] + b_o[n0 + nl]);
        float tc = fast_tanh(Pc[idx] + b_C[n0 + nl]);
        float C  = f * C_prev[idx] + ii * tc;
        float h  = o * fast_tanh(C);
        outC[idx] = C;
        outH[idx] = h;
        T[nl * 66 + bi] = (unsigned short)f2bf(h);
    }
    __syncthreads();
    #pragma unroll
    for (int i = 0; i < 16; i++) {
        int r = wv + i * 4;   // local b index
        h_t[(size_t)(b0 + r) * DN + n0 + bi] = T[bi * 66 + r];
    }
}

// ---------------------------------------------------------------------------
extern "C" void kernel_launch(void* const* d_in, const int* in_sizes, int n_in,
                              void* d_out, int out_size, void* d_ws, size_t ws_size,
                              hipStream_t stream)
{
    const int*   input_text = (const int*)d_in[0];
    const float* h_prev = (const float*)d_in[1];
    const float* C_prev = (const float*)d_in[2];
    const float* emb    = (const float*)d_in[3];
    const float* W_A    = (const float*)d_in[4];
    const float* W_C    = (const float*)d_in[5];
    const float* W_f    = (const float*)d_in[6];
    const float* W_o    = (const float*)d_in[7];
    const float* W_i    = (const float*)d_in[8];
    const float* b_A    = (const float*)d_in[9];
    const float* b_C    = (const float*)d_in[10];
    const float* b_f    = (const float*)d_in[11];
    const float* b_o    = (const float*)d_in[12];
    const float* b_i    = (const float*)d_in[13];

    // workspace layout (88,080,384 bytes total)
    char* ws = (char*)d_ws;
    unsigned short* z_t = (unsigned short*)ws;                       // 2048*3072*2 = 12,582,912
    float* Pf = (float*)(ws + 12582912);                             // 4x 2048*2048*4
    float* Pi = (float*)(ws + 12582912 + 1 * 16777216);
    float* Po = (float*)(ws + 12582912 + 2 * 16777216);
    float* Pc = (float*)(ws + 12582912 + 3 * 16777216);
    unsigned short* h_t = (unsigned short*)(ws + 12582912 + 4 * 16777216); // 2048*2048*2

    float* y    = (float*)d_out;                      // [32000, 2048]
    float* outH = y + (size_t)DM * DB;                // [2048, 2048]
    float* outC = outH + (size_t)DN * DB;             // [2048, 2048]

    // 1. z^T build: h part (transpose) + emb part (gather)
    transpose_h_kernel<<<dim3(32, 32), 256, 0, stream>>>(h_prev, z_t);
    emb_gather_kernel<<<dim3(2048), 256, 0, stream>>>(input_text, emb, z_t);

    // 2. fused 4-gate GEMM: P_g = W_g @ z   (grid.z = gate)
    gemm_bt_kernel<<<dim3(16, 16, 4), 256, 0, stream>>>(
        W_f, W_i, W_o, W_C, z_t, Pf, Pi, Po, Pc, nullptr, DKG);

    // 3. gates -> C, h, h^T
    pointwise_kernel<<<dim3(32, 32), 256, 0, stream>>>(
        Pf, Pi, Po, Pc, C_prev, b_f, b_i, b_o, b_C, outH, outC, h_t);

    // 4. y = W_A @ h + b_A
    gemm_bt_kernel<<<dim3(16, 250, 1), 256, 0, stream>>>(
        W_A, W_A, W_A, W_A, h_t, y, y, y, y, b_A, DN);
}